// Round 11
// baseline (116.366 us; speedup 1.0000x reference)
//
#include <hip/hip_runtime.h>
#include <hip/hip_bf16.h>

// NeighbourhoodAttnBlock: B=2, H=W=64, D=512, NH=8, DH=64, KERNEL=7
// Inputs fp32; output fp32. Internal pipeline bf16 MFMA.
// R11 = R10 (verified best 113.9us) + T5 s_setprio(1) around attn's two
// MFMA clusters (QK^T, PV). Mechanism-matched: independent wgs/waves at
// different phases on each CU (m191: attn +4-7%; m190: null only for
// barrier-lockstep GEMM). Zero arithmetic/sync change.
// Ledger 135.5 -> 113.9: (R4) swapped-QK^T attn, sbuf eliminated, 29.7KB
// LDS, 4 wg/CU; (R5) XCD chunked swizzle all grids + unnormalized P +
// deferred 1/ssum; (R6) gemm1 LDS re-layout epilogue. gemm1 = 680 TF =
// measured 2-phase-structure ceiling (m230/m248); 8-phase port blocked by
// 75% grid underfill at 256^2 on this shape + single-shot race risk.
// Neg/null: R8 pipeline+nt (+5.5), R9 BN=64 (+2.7), R3 T14 V-prefetch (0).

typedef __bf16 bf16x8 __attribute__((ext_vector_type(8)));
typedef __bf16 bf16x4 __attribute__((ext_vector_type(4)));
typedef __bf16 bf16x2 __attribute__((ext_vector_type(2)));
typedef float  f32x4  __attribute__((ext_vector_type(4)));
typedef int    i32x4  __attribute__((ext_vector_type(4)));

__global__ __launch_bounds__(256) void cvt_all(
    const float* __restrict__ x, const float* __restrict__ wq,
    const float* __restrict__ wo, __bf16* __restrict__ xb,
    __bf16* __restrict__ wqb, __bf16* __restrict__ wob) {
  // 655360 chunks of 2x f32x4 (32B read / 16B write per thread)
  int i = blockIdx.x * 256 + threadIdx.x;
  const float* src;
  __bf16* dst;
  int j = i;
  if (j < 524288) {
    src = x; dst = xb;
  } else if (j < 524288 + 98304) {
    j -= 524288; src = wq; dst = wqb;
  } else {
    j -= 524288 + 98304; src = wo; dst = wob;
  }
  f32x4 v0 = ((const f32x4*)src)[j * 2];
  f32x4 v1 = ((const f32x4*)src)[j * 2 + 1];
  bf16x8 o;
  o[0] = (__bf16)v0[0]; o[1] = (__bf16)v0[1];
  o[2] = (__bf16)v0[2]; o[3] = (__bf16)v0[3];
  o[4] = (__bf16)v1[0]; o[5] = (__bf16)v1[1];
  o[6] = (__bf16)v1[2]; o[7] = (__bf16)v1[3];
  ((bf16x8*)dst)[j] = o;
}

__device__ __forceinline__ void gload_lds16(const __bf16* g, __bf16* l) {
  __builtin_amdgcn_global_load_lds(
      (const __attribute__((address_space(1))) void*)g,
      (__attribute__((address_space(3))) void*)l, 16, 0, 0);
}

// C[i][e] = sum_d A[i][d] * W[e][d];  A:[M,512], W:[E,512] row-major bf16.
// 128xBN block tile, 4 waves x (64 x BN/2). BK=64 via two contiguous 32-col
// half-buffers (global_load_lds needs unpadded contiguity).
template <bool QKV, int BN>
__global__ __launch_bounds__(256, 3) void gemm_lds(
    const __bf16* __restrict__ A, const __bf16* __restrict__ W,
    __bf16* __restrict__ qo, __bf16* __restrict__ ko, __bf16* __restrict__ vo,
    float* __restrict__ co, int etiles) {
  constexpr int K = 512;
  constexpr int NT = BN / 32;
  constexpr int WHALF = BN * 32;
  // Single contiguous LDS pool: Al | Wl during K-loop; reused as the
  // 128xBN bf16 C-tile (ct) in the QKV epilogue (sizes match: 16384).
  __shared__ alignas(16) __bf16 shm[2 * 128 * 32 + 2 * WHALF];
  __bf16* Al = shm;
  __bf16* Wl = shm + 2 * 128 * 32;
  __bf16* ct = shm;
  const int tid = threadIdx.x;
  const int wv = tid >> 6, lane = tid & 63;
  const int n16 = lane & 15, quad = lane >> 4;
  // T1 XCD chunked swizzle (gridDim.x % 8 == 0 -> bijective):
  // each XCD gets a contiguous chunk of tiles -> A-panels + W fit its L2.
  const int nper = (int)gridDim.x >> 3;
  const int wg = (blockIdx.x & 7) * nper + (blockIdx.x >> 3);
  const int bi = wg / etiles, be = wg % etiles;
  const int i0 = bi << 7, e0 = be * BN;
  const int wm = (wv & 1) << 6, we = (wv >> 1) * (BN / 2);

  const int srow = (wv << 4) + (lane >> 2);
  const int scol = (lane & 3) << 3;
  const __bf16* gA = A + (size_t)(i0 + srow) * K + scol;
  const __bf16* gW = W + (size_t)(e0 + srow) * K + scol;
  const int soff = (wv << 9) + (lane << 3);

  f32x4 acc[4][NT];
#pragma unroll
  for (int a = 0; a < 4; ++a)
#pragma unroll
    for (int b = 0; b < NT; ++b) acc[a][b] = (f32x4){0.f, 0.f, 0.f, 0.f};

  for (int k0 = 0; k0 < K; k0 += 64) {
    if (k0) __syncthreads();
#pragma unroll
    for (int h = 0; h < 2; ++h) {
      gload_lds16(gA + k0 + h * 32, &Al[h * 4096 + soff]);
      gload_lds16(gA + (size_t)64 * K + k0 + h * 32,
                  &Al[h * 4096 + 64 * 32 + soff]);
      gload_lds16(gW + k0 + h * 32, &Wl[h * WHALF + soff]);
      if (BN == 128)
        gload_lds16(gW + (size_t)64 * K + k0 + h * 32,
                    &Wl[h * WHALF + 64 * 32 + soff]);
    }
    __syncthreads();

#pragma unroll
    for (int h = 0; h < 2; ++h) {
      bf16x8 af[4], wf[NT];
#pragma unroll
      for (int t = 0; t < 4; ++t)
        af[t] = *(const bf16x8*)&Al[h * 4096 + (wm + t * 16 + n16) * 32 +
                                    quad * 8];
#pragma unroll
      for (int t = 0; t < NT; ++t)
        wf[t] = *(const bf16x8*)&Wl[h * WHALF + (we + t * 16 + n16) * 32 +
                                    quad * 8];
#pragma unroll
      for (int mt = 0; mt < 4; ++mt)
#pragma unroll
        for (int nt = 0; nt < NT; ++nt)
          acc[mt][nt] = __builtin_amdgcn_mfma_f32_16x16x32_bf16(
              af[mt], wf[nt], acc[mt][nt], 0, 0, 0);
    }
  }

  if (QKV) {
    // ---- LDS re-layout epilogue (block type is uniform: tsel=e0>>9) ----
    __syncthreads();  // all waves done reading Al/Wl
    const int tsel = e0 >> 9;  // 0=q, 1=k, 2=v
    if (tsel == 2) {
      // transposed ct[e][i ^ sw] via b64 (rg values are consecutive i)
#pragma unroll
      for (int mt = 0; mt < 4; ++mt)
#pragma unroll
        for (int nt = 0; nt < NT; ++nt) {
          f32x4 f = acc[mt][nt];
          int el = we + nt * 16 + n16;
          int il = wm + mt * 16 + quad * 4;
          bf16x4 h4 = {(__bf16)f[0], (__bf16)f[1], (__bf16)f[2], (__bf16)f[3]};
          *(bf16x4*)&ct[el * 128 + (il ^ ((el & 7) << 3))] = h4;
        }
    } else {
      const float qs = (tsel == 0) ? 0.125f : 1.0f;  // fold attn scale into q
#pragma unroll
      for (int mt = 0; mt < 4; ++mt)
#pragma unroll
        for (int nt = 0; nt < NT; ++nt) {
          f32x4 f = acc[mt][nt];
          int el = we + nt * 16 + n16;
#pragma unroll
          for (int rg = 0; rg < 4; ++rg) {
            int il = wm + mt * 16 + quad * 4 + rg;
            ct[il * 128 + (el ^ ((il & 7) << 3))] = (__bf16)(f[rg] * qs);
          }
        }
    }
    __syncthreads();
    // ---- common drain: 2048 chunks of 8, fully coalesced 16B stores ----
    const int b = i0 >> 12;
    const int s0 = i0 & 4095;
#pragma unroll
    for (int u = 0; u < 8; ++u) {
      int cid = u * 256 + tid;
      int row = cid >> 4, c8 = (cid & 15) << 3;
      bf16x8 d = *(const bf16x8*)&ct[row * 128 + (c8 ^ ((row & 7) << 3))];
      if (tsel == 2) {
        int e = e0 + row;  // row = e_local
        int head = (e >> 6) & 7, dh = e & 63;
        *(bf16x8*)&vo[((size_t)(b * 8 + head) * 64 + dh) * 4096 + s0 + c8] = d;
      } else {
        int e = e0 + c8;   // row = i_local
        int head = (e >> 6) & 7, dh = e & 63;
        size_t off = ((size_t)(b * 8 + head) * 4096 + (s0 + row)) * 64 + dh;
        *(bf16x8*)&((tsel == 0) ? qo : ko)[off] = d;
      }
    }
  } else {
    // ---- fp32 C output (out GEMM), unchanged ----
#pragma unroll
    for (int mt = 0; mt < 4; ++mt)
#pragma unroll
      for (int nt = 0; nt < NT; ++nt) {
        f32x4 f = acc[mt][nt];
        int e = e0 + we + nt * 16 + n16;
#pragma unroll
        for (int rg = 0; rg < 4; ++rg) {
          int i = i0 + wm + mt * 16 + quad * 4 + rg;
          co[(size_t)i * 512 + e] = f[rg];
        }
      }
  }
}

// MFMA neighbourhood attention, swapped-QK^T / in-register-P version.
// One workgroup per (bh, 8x8 query tile). LDS = kwin/vwin only (29.7 KB).
// Phase 1: K window -> LDS (pre-swizzled gload_lds); S^T = mfma(K,Q);
//          per-lane mask + softmax (one q per lane); P packed UNNORMALIZED
//          to bf16 regs (exp <= 1); 1/ssum applied to O after PV.
// Phase 2: barrier; V window -> LDS [dh][232]; PV with per-kt in-register
//          P gather (8 shfl quad-exchange) -> mfma(pa, vb).
// T5: setprio(1) around both MFMA clusters (independent wgs per CU ->
// scheduler role-diversity; m191 +4-7% attn).
__global__ __launch_bounds__(256, 4) void attn_mfma(
    const __bf16* __restrict__ q, const __bf16* __restrict__ k,
    const __bf16* __restrict__ vt, __bf16* __restrict__ out) {
  __shared__ alignas(16) __bf16 r1[14848];  // kwin / vwin[64][232]
  const int tid = threadIdx.x;
  const int wv = tid >> 6;
  const int lane = tid & 63;
  const int n16 = lane & 15, quad = lane >> 4;
  // T1 XCD chunked swizzle: 1024 wgs -> each XCD owns 128 contiguous wgs
  // = 2 whole bh (q+k+vt = 3.1MB < 4MB L2): window overlap re-reads hit L2.
  const int wg = ((blockIdx.x & 7) << 7) + (blockIdx.x >> 3);
  const int bh = wg >> 6;
  const int tile = wg & 63;
  const int qh0 = (tile >> 3) << 3, qw0 = (tile & 7) << 3;
  int wh0 = qh0 - 3; wh0 = wh0 < 0 ? 0 : (wh0 > 50 ? 50 : wh0);
  int wc0 = qw0 - 3; wc0 = wc0 < 0 ? 0 : (wc0 > 48 ? 48 : wc0);
  wc0 &= ~1;  // window covers [qw0-3, qw0+10]
  const size_t base = (size_t)bh * 4096 * 64;

  // ---- Q frags (B-operand of swapped QK^T; layout identical to A-frag) ----
  const int qi = wv * 16 + n16;  // this lane's query (softmax row)
  const int sq = (qh0 + (qi >> 3)) * 64 + qw0 + (qi & 7);
  const __bf16* qp = q + base + (size_t)sq * 64 + quad * 8;
  bf16x8 bq0 = *(const bf16x8*)qp;
  bf16x8 bq1 = *(const bf16x8*)(qp + 32);

  // ---- K window staging: global_load_lds, source pre-swizzled (R3-verified)
  const __bf16* kbase = k + base;
#pragma unroll
  for (int i = 0; i < 7; ++i) {
    int ch = i * 256 + tid;           // 1792 16-B chunks
    int kr = ch >> 7, wi = ch & 127;
    int kc = wi >> 3, dh8 = wi & 7;
    gload_lds16(kbase + (size_t)((wh0 + kr) * 64 + wc0 + kc) * 64 +
                    ((dh8 ^ (kc & 7)) * 8),
                &r1[ch * 8]);
  }
  __syncthreads();

  // ---- swapped QK^T: S[nt] = S^T tile; lane = [key=nt*16+quad*4+reg][q=n16]
  f32x4 S[14];
  const int sw1 = ((quad ^ (n16 & 7)) * 8);
  const int sw2 = (((4 + quad) ^ (n16 & 7)) * 8);
  __builtin_amdgcn_s_setprio(1);  // T5: favor this wave's MFMA cluster
#pragma unroll
  for (int nt = 0; nt < 14; ++nt) {
    int key = nt * 16 + n16;
    bf16x8 kf0 = *(const bf16x8*)&r1[key * 64 + sw1];
    bf16x8 kf1 = *(const bf16x8*)&r1[key * 64 + sw2];
    f32x4 s = {0.f, 0.f, 0.f, 0.f};
    s = __builtin_amdgcn_mfma_f32_16x16x32_bf16(kf0, bq0, s, 0, 0, 0);
    s = __builtin_amdgcn_mfma_f32_16x16x32_bf16(kf1, bq1, s, 0, 0, 0);
    S[nt] = s;
  }
  __builtin_amdgcn_s_setprio(0);

  // ---- mask (scale already folded into q): one query per lane ----
  const int qh = qh0 + (qi >> 3), qw = qw0 + (qi & 7);
  int sh = qh - 3; sh = sh < 0 ? 0 : (sh > 57 ? 57 : sh);
  int sw = qw - 3; sw = sw < 0 ? 0 : (sw > 57 ? 57 : sw);
  const int lo = sh - wh0;  // valid key-rows: nt in [lo, lo+7)
  bool wok[4];
#pragma unroll
  for (int reg = 0; reg < 4; ++reg) {
    int kw = wc0 + quad * 4 + reg;  // fixed key col per (lane,reg)
    wok[reg] = (kw >= sw) && (kw < sw + 7);
  }
  float mx[4] = {-1e30f, -1e30f, -1e30f, -1e30f};
#pragma unroll
  for (int nt = 0; nt < 14; ++nt) {
    bool rok = (unsigned)(nt - lo) < 7u;
#pragma unroll
    for (int reg = 0; reg < 4; ++reg) {
      float val = (rok && wok[reg]) ? S[nt][reg] : -1e30f;
      S[nt][reg] = val;
      mx[reg] = mx[reg] > val ? mx[reg] : val;
    }
  }
  float m = fmaxf(fmaxf(mx[0], mx[1]), fmaxf(mx[2], mx[3]));
  m = fmaxf(m, __shfl_xor(m, 16));
  m = fmaxf(m, __shfl_xor(m, 32));

  // ---- exp + row sum; pack UNNORMALIZED P (exp <= 1, bf16-safe) ----
  int plo[14], phi[14];
  float sm[4] = {0.f, 0.f, 0.f, 0.f};
#pragma unroll
  for (int nt = 0; nt < 14; ++nt) {
    float p0 = __expf(S[nt][0] - m);
    float p1 = __expf(S[nt][1] - m);
    float p2 = __expf(S[nt][2] - m);
    float p3 = __expf(S[nt][3] - m);
    sm[0] += p0; sm[1] += p1; sm[2] += p2; sm[3] += p3;
    bf16x2 a = {(__bf16)p0, (__bf16)p1};
    bf16x2 b = {(__bf16)p2, (__bf16)p3};
    plo[nt] = __builtin_bit_cast(int, a);
    phi[nt] = __builtin_bit_cast(int, b);
  }
  float ssum = (sm[0] + sm[1]) + (sm[2] + sm[3]);
  ssum += __shfl_xor(ssum, 16);
  ssum += __shfl_xor(ssum, 32);
  const float inv = 1.f / ssum;  // for q = wv*16 + n16

  __syncthreads();  // all waves done reading kwin
  // ---- V coop load: global -> vwin[dh][232] (key = kr*16+kc) ----
  const __bf16* vtb = vt + base;
#pragma unroll
  for (int i = 0; i < 7; ++i) {
    int c = i * 256 + tid;  // 1792 16-B chunks: c = dh*28 + kr*2 + half
    int dh = c / 28, rem = c % 28;
    int kr = rem >> 1, half = rem & 1;
    bf16x8 d = *(const bf16x8*)(vtb + (size_t)dh * 4096 +
                                (wh0 + kr) * 64 + wc0 + half * 8);
    *(bf16x8*)&r1[dh * 232 + kr * 16 + half * 8] = d;
  }
  __syncthreads();

  // ---- PV: O[16q x 64dh]; A-frag gathered in-register per kt ----
  // pa elem j = P[key=kt*32+quad*8+j][q=n16]. Source lane holds key-col
  // quad_s*4+reg at q=n16 -> gather from lanes s0=((quad&1)*2)*16+n16 and
  // s1=s0+16; key-row parity: quads 0,1 need nt=2kt, quads 2,3 nt=2kt+1.
  f32x4 O[4] = {{0.f, 0.f, 0.f, 0.f},
                {0.f, 0.f, 0.f, 0.f},
                {0.f, 0.f, 0.f, 0.f},
                {0.f, 0.f, 0.f, 0.f}};
  const int s0 = ((quad & 1) << 5) + n16;
  const int s1 = s0 + 16;
  const bool hiq = quad >= 2;
  __builtin_amdgcn_s_setprio(1);  // T5: PV cluster (shfl feeds MFMA)
#pragma unroll
  for (int kt = 0; kt < 7; ++kt) {
    const int nA = 2 * kt, nB = 2 * kt + 1;
    int a0 = __shfl(plo[nA], s0), a1 = __shfl(phi[nA], s0);
    int a2 = __shfl(plo[nA], s1), a3 = __shfl(phi[nA], s1);
    int b0 = __shfl(plo[nB], s0), b1 = __shfl(phi[nB], s0);
    int b2 = __shfl(plo[nB], s1), b3 = __shfl(phi[nB], s1);
    i32x4 pu = {hiq ? b0 : a0, hiq ? b1 : a1, hiq ? b2 : a2, hiq ? b3 : a3};
    bf16x8 pa = __builtin_bit_cast(bf16x8, pu);
    const int key0 = kt * 32 + quad * 8;
#pragma unroll
    for (int ntv = 0; ntv < 4; ++ntv) {
      bf16x8 vb = *(const bf16x8*)&r1[(ntv * 16 + n16) * 232 + key0];
      O[ntv] = __builtin_amdgcn_mfma_f32_16x16x32_bf16(pa, vb, O[ntv], 0, 0, 0);
    }
  }
  __builtin_amdgcn_s_setprio(0);

  // ---- deferred normalization: inv for O-row q'=quad*4+reg via shfl ----
  float invr[4];
#pragma unroll
  for (int reg = 0; reg < 4; ++reg) invr[reg] = __shfl(inv, quad * 4 + reg);

  // ---- epilogue: ao[b][s][head*64+dh] bf16 (O rows: q=quad*4+reg) ----
  const int b = bh >> 3, head = bh & 7;
#pragma unroll
  for (int ntv = 0; ntv < 4; ++ntv)
#pragma unroll
    for (int reg = 0; reg < 4; ++reg) {
      int qe = wv * 16 + quad * 4 + reg;
      int s_q = (qh0 + (qe >> 3)) * 64 + qw0 + (qe & 7);
      int dh = ntv * 16 + n16;
      out[((size_t)(b * 4096 + s_q)) * 512 + head * 64 + dh] =
          (__bf16)(O[ntv][reg] * invr[reg]);
    }
}

extern "C" void kernel_launch(void* const* d_in, const int* in_sizes, int n_in,
                              void* d_out, int out_size, void* d_ws,
                              size_t ws_size, hipStream_t stream) {
  const float* x = (const float*)d_in[0];      // [2,64,64,512] fp32
  const float* w_qkv = (const float*)d_in[1];  // [1536,512] fp32
  const float* w_out = (const float*)d_in[2];  // [512,512] fp32
  float* out = (float*)d_out;                  // [2,64,64,512] fp32

  const size_t qelems = (size_t)2 * 8 * 4096 * 64;  // 4,194,304
  __bf16* q = (__bf16*)d_ws;
  __bf16* k = q + qelems;
  __bf16* vt = k + qelems;          // V transposed [bh][dh][s]
  __bf16* xb = vt + qelems;         // converted x; reused as ao
  __bf16* wqb = xb + qelems;        // converted w_qkv
  __bf16* wob = wqb + 1536 * 512;   // converted w_out
  __bf16* ao = xb;                  // attn out aliases xb (x dead after QKV)

  // Stage 0: fused fp32 -> bf16 (655360 chunks of 2x f32x4)
  cvt_all<<<dim3(2560), dim3(256), 0, stream>>>(x, w_qkv, w_out, xb, wqb, wob);

  // Stage 1: QKV GEMM: 64 i-tiles x 12 e-tiles = 768 blocks (3/CU)
  gemm_lds<true, 128><<<dim3(768), dim3(256), 0, stream>>>(
      xb, wqb, q, k, vt, nullptr, 12);
  // Stage 2: MFMA attention: 16 bh * 64 tiles = 1024 workgroups (4/CU)
  attn_mfma<<<dim3(1024), dim3(256), 0, stream>>>(q, k, vt, ao);
  // Stage 3: out GEMM: 64 i-tiles x 8 e-tiles = 512 blocks
  gemm_lds<false, 64><<<dim3(512), dim3(256), 0, stream>>>(
      ao, wob, nullptr, nullptr, nullptr, out, 8);
}

// Round 12
// 113.548 us; speedup vs baseline: 1.0248x; 1.0248x over previous
//
#include <hip/hip_runtime.h>
#include <hip/hip_bf16.h>

// NeighbourhoodAttnBlock: B=2, H=W=64, D=512, NH=8, DH=64, KERNEL=7
// Inputs fp32; output fp32. Internal pipeline bf16 MFMA.
// R12 = R10 restore (verified best: 113.9us; R11's T5 setprio +2.5
// reverted -- 4-wave barrier-synced blocks starve co-resident staging
// waves, m190-like not m191-like).
// Session ledger 135.5 -> 113.9: (R4) swapped-QK^T attn, sbuf eliminated,
// 29.7KB LDS, 4 wg/CU; (R5) XCD chunked swizzle all grids + unnormalized
// P + deferred 1/ssum; (R6) gemm1 LDS re-layout epilogue (coalesced 16B
// q/k/vt stores, v transposed in LDS). gemm1 = 680 TF = measured 2-phase
// structure ceiling (m230/m248). Nulls/regs: T14 V-prefetch (0), R8
// pipeline+nt (+5.5), R9 BN=64 (+2.7), R11 setprio (+2.5). ~72-90us of
// dur_us is harness poison-fill (uncontrollable).

typedef __bf16 bf16x8 __attribute__((ext_vector_type(8)));
typedef __bf16 bf16x4 __attribute__((ext_vector_type(4)));
typedef __bf16 bf16x2 __attribute__((ext_vector_type(2)));
typedef float  f32x4  __attribute__((ext_vector_type(4)));
typedef int    i32x4  __attribute__((ext_vector_type(4)));

__global__ __launch_bounds__(256) void cvt_all(
    const float* __restrict__ x, const float* __restrict__ wq,
    const float* __restrict__ wo, __bf16* __restrict__ xb,
    __bf16* __restrict__ wqb, __bf16* __restrict__ wob) {
  // 655360 chunks of 2x f32x4 (32B read / 16B write per thread)
  int i = blockIdx.x * 256 + threadIdx.x;
  const float* src;
  __bf16* dst;
  int j = i;
  if (j < 524288) {
    src = x; dst = xb;
  } else if (j < 524288 + 98304) {
    j -= 524288; src = wq; dst = wqb;
  } else {
    j -= 524288 + 98304; src = wo; dst = wob;
  }
  f32x4 v0 = ((const f32x4*)src)[j * 2];
  f32x4 v1 = ((const f32x4*)src)[j * 2 + 1];
  bf16x8 o;
  o[0] = (__bf16)v0[0]; o[1] = (__bf16)v0[1];
  o[2] = (__bf16)v0[2]; o[3] = (__bf16)v0[3];
  o[4] = (__bf16)v1[0]; o[5] = (__bf16)v1[1];
  o[6] = (__bf16)v1[2]; o[7] = (__bf16)v1[3];
  ((bf16x8*)dst)[j] = o;
}

__device__ __forceinline__ void gload_lds16(const __bf16* g, __bf16* l) {
  __builtin_amdgcn_global_load_lds(
      (const __attribute__((address_space(1))) void*)g,
      (__attribute__((address_space(3))) void*)l, 16, 0, 0);
}

// C[i][e] = sum_d A[i][d] * W[e][d];  A:[M,512], W:[E,512] row-major bf16.
// 128xBN block tile, 4 waves x (64 x BN/2). BK=64 via two contiguous 32-col
// half-buffers (global_load_lds needs unpadded contiguity).
template <bool QKV, int BN>
__global__ __launch_bounds__(256, 3) void gemm_lds(
    const __bf16* __restrict__ A, const __bf16* __restrict__ W,
    __bf16* __restrict__ qo, __bf16* __restrict__ ko, __bf16* __restrict__ vo,
    float* __restrict__ co, int etiles) {
  constexpr int K = 512;
  constexpr int NT = BN / 32;
  constexpr int WHALF = BN * 32;
  // Single contiguous LDS pool: Al | Wl during K-loop; reused as the
  // 128xBN bf16 C-tile (ct) in the QKV epilogue (sizes match: 16384).
  __shared__ alignas(16) __bf16 shm[2 * 128 * 32 + 2 * WHALF];
  __bf16* Al = shm;
  __bf16* Wl = shm + 2 * 128 * 32;
  __bf16* ct = shm;
  const int tid = threadIdx.x;
  const int wv = tid >> 6, lane = tid & 63;
  const int n16 = lane & 15, quad = lane >> 4;
  // T1 XCD chunked swizzle (gridDim.x % 8 == 0 -> bijective):
  // each XCD gets a contiguous chunk of tiles -> A-panels + W fit its L2.
  const int nper = (int)gridDim.x >> 3;
  const int wg = (blockIdx.x & 7) * nper + (blockIdx.x >> 3);
  const int bi = wg / etiles, be = wg % etiles;
  const int i0 = bi << 7, e0 = be * BN;
  const int wm = (wv & 1) << 6, we = (wv >> 1) * (BN / 2);

  const int srow = (wv << 4) + (lane >> 2);
  const int scol = (lane & 3) << 3;
  const __bf16* gA = A + (size_t)(i0 + srow) * K + scol;
  const __bf16* gW = W + (size_t)(e0 + srow) * K + scol;
  const int soff = (wv << 9) + (lane << 3);

  f32x4 acc[4][NT];
#pragma unroll
  for (int a = 0; a < 4; ++a)
#pragma unroll
    for (int b = 0; b < NT; ++b) acc[a][b] = (f32x4){0.f, 0.f, 0.f, 0.f};

  for (int k0 = 0; k0 < K; k0 += 64) {
    if (k0) __syncthreads();
#pragma unroll
    for (int h = 0; h < 2; ++h) {
      gload_lds16(gA + k0 + h * 32, &Al[h * 4096 + soff]);
      gload_lds16(gA + (size_t)64 * K + k0 + h * 32,
                  &Al[h * 4096 + 64 * 32 + soff]);
      gload_lds16(gW + k0 + h * 32, &Wl[h * WHALF + soff]);
      if (BN == 128)
        gload_lds16(gW + (size_t)64 * K + k0 + h * 32,
                    &Wl[h * WHALF + 64 * 32 + soff]);
    }
    __syncthreads();

#pragma unroll
    for (int h = 0; h < 2; ++h) {
      bf16x8 af[4], wf[NT];
#pragma unroll
      for (int t = 0; t < 4; ++t)
        af[t] = *(const bf16x8*)&Al[h * 4096 + (wm + t * 16 + n16) * 32 +
                                    quad * 8];
#pragma unroll
      for (int t = 0; t < NT; ++t)
        wf[t] = *(const bf16x8*)&Wl[h * WHALF + (we + t * 16 + n16) * 32 +
                                    quad * 8];
#pragma unroll
      for (int mt = 0; mt < 4; ++mt)
#pragma unroll
        for (int nt = 0; nt < NT; ++nt)
          acc[mt][nt] = __builtin_amdgcn_mfma_f32_16x16x32_bf16(
              af[mt], wf[nt], acc[mt][nt], 0, 0, 0);
    }
  }

  if (QKV) {
    // ---- LDS re-layout epilogue (block type is uniform: tsel=e0>>9) ----
    __syncthreads();  // all waves done reading Al/Wl
    const int tsel = e0 >> 9;  // 0=q, 1=k, 2=v
    if (tsel == 2) {
      // transposed ct[e][i ^ sw] via b64 (rg values are consecutive i)
#pragma unroll
      for (int mt = 0; mt < 4; ++mt)
#pragma unroll
        for (int nt = 0; nt < NT; ++nt) {
          f32x4 f = acc[mt][nt];
          int el = we + nt * 16 + n16;
          int il = wm + mt * 16 + quad * 4;
          bf16x4 h4 = {(__bf16)f[0], (__bf16)f[1], (__bf16)f[2], (__bf16)f[3]};
          *(bf16x4*)&ct[el * 128 + (il ^ ((el & 7) << 3))] = h4;
        }
    } else {
      const float qs = (tsel == 0) ? 0.125f : 1.0f;  // fold attn scale into q
#pragma unroll
      for (int mt = 0; mt < 4; ++mt)
#pragma unroll
        for (int nt = 0; nt < NT; ++nt) {
          f32x4 f = acc[mt][nt];
          int el = we + nt * 16 + n16;
#pragma unroll
          for (int rg = 0; rg < 4; ++rg) {
            int il = wm + mt * 16 + quad * 4 + rg;
            ct[il * 128 + (el ^ ((il & 7) << 3))] = (__bf16)(f[rg] * qs);
          }
        }
    }
    __syncthreads();
    // ---- common drain: 2048 chunks of 8, fully coalesced 16B stores ----
    const int b = i0 >> 12;
    const int s0 = i0 & 4095;
#pragma unroll
    for (int u = 0; u < 8; ++u) {
      int cid = u * 256 + tid;
      int row = cid >> 4, c8 = (cid & 15) << 3;
      bf16x8 d = *(const bf16x8*)&ct[row * 128 + (c8 ^ ((row & 7) << 3))];
      if (tsel == 2) {
        int e = e0 + row;  // row = e_local
        int head = (e >> 6) & 7, dh = e & 63;
        *(bf16x8*)&vo[((size_t)(b * 8 + head) * 64 + dh) * 4096 + s0 + c8] = d;
      } else {
        int e = e0 + c8;   // row = i_local
        int head = (e >> 6) & 7, dh = e & 63;
        size_t off = ((size_t)(b * 8 + head) * 4096 + (s0 + row)) * 64 + dh;
        *(bf16x8*)&((tsel == 0) ? qo : ko)[off] = d;
      }
    }
  } else {
    // ---- fp32 C output (out GEMM), unchanged ----
#pragma unroll
    for (int mt = 0; mt < 4; ++mt)
#pragma unroll
      for (int nt = 0; nt < NT; ++nt) {
        f32x4 f = acc[mt][nt];
        int e = e0 + we + nt * 16 + n16;
#pragma unroll
        for (int rg = 0; rg < 4; ++rg) {
          int i = i0 + wm + mt * 16 + quad * 4 + rg;
          co[(size_t)i * 512 + e] = f[rg];
        }
      }
  }
}

// MFMA neighbourhood attention, swapped-QK^T / in-register-P version.
// One workgroup per (bh, 8x8 query tile). LDS = kwin/vwin only (29.7 KB).
// Phase 1: K window -> LDS (pre-swizzled gload_lds); S^T = mfma(K,Q);
//          per-lane mask + softmax (one q per lane); P packed UNNORMALIZED
//          to bf16 regs (exp <= 1); 1/ssum applied to O after PV.
// Phase 2: barrier; V window -> LDS [dh][232]; PV with per-kt in-register
//          P gather (8 shfl quad-exchange) -> mfma(pa, vb).
__global__ __launch_bounds__(256, 4) void attn_mfma(
    const __bf16* __restrict__ q, const __bf16* __restrict__ k,
    const __bf16* __restrict__ vt, __bf16* __restrict__ out) {
  __shared__ alignas(16) __bf16 r1[14848];  // kwin / vwin[64][232]
  const int tid = threadIdx.x;
  const int wv = tid >> 6;
  const int lane = tid & 63;
  const int n16 = lane & 15, quad = lane >> 4;
  // T1 XCD chunked swizzle: 1024 wgs -> each XCD owns 128 contiguous wgs
  // = 2 whole bh (q+k+vt = 3.1MB < 4MB L2): window overlap re-reads hit L2.
  const int wg = ((blockIdx.x & 7) << 7) + (blockIdx.x >> 3);
  const int bh = wg >> 6;
  const int tile = wg & 63;
  const int qh0 = (tile >> 3) << 3, qw0 = (tile & 7) << 3;
  int wh0 = qh0 - 3; wh0 = wh0 < 0 ? 0 : (wh0 > 50 ? 50 : wh0);
  int wc0 = qw0 - 3; wc0 = wc0 < 0 ? 0 : (wc0 > 48 ? 48 : wc0);
  wc0 &= ~1;  // window covers [qw0-3, qw0+10]
  const size_t base = (size_t)bh * 4096 * 64;

  // ---- Q frags (B-operand of swapped QK^T; layout identical to A-frag) ----
  const int qi = wv * 16 + n16;  // this lane's query (softmax row)
  const int sq = (qh0 + (qi >> 3)) * 64 + qw0 + (qi & 7);
  const __bf16* qp = q + base + (size_t)sq * 64 + quad * 8;
  bf16x8 bq0 = *(const bf16x8*)qp;
  bf16x8 bq1 = *(const bf16x8*)(qp + 32);

  // ---- K window staging: global_load_lds, source pre-swizzled (R3-verified)
  const __bf16* kbase = k + base;
#pragma unroll
  for (int i = 0; i < 7; ++i) {
    int ch = i * 256 + tid;           // 1792 16-B chunks
    int kr = ch >> 7, wi = ch & 127;
    int kc = wi >> 3, dh8 = wi & 7;
    gload_lds16(kbase + (size_t)((wh0 + kr) * 64 + wc0 + kc) * 64 +
                    ((dh8 ^ (kc & 7)) * 8),
                &r1[ch * 8]);
  }
  __syncthreads();

  // ---- swapped QK^T: S[nt] = S^T tile; lane = [key=nt*16+quad*4+reg][q=n16]
  f32x4 S[14];
  const int sw1 = ((quad ^ (n16 & 7)) * 8);
  const int sw2 = (((4 + quad) ^ (n16 & 7)) * 8);
#pragma unroll
  for (int nt = 0; nt < 14; ++nt) {
    int key = nt * 16 + n16;
    bf16x8 kf0 = *(const bf16x8*)&r1[key * 64 + sw1];
    bf16x8 kf1 = *(const bf16x8*)&r1[key * 64 + sw2];
    f32x4 s = {0.f, 0.f, 0.f, 0.f};
    s = __builtin_amdgcn_mfma_f32_16x16x32_bf16(kf0, bq0, s, 0, 0, 0);
    s = __builtin_amdgcn_mfma_f32_16x16x32_bf16(kf1, bq1, s, 0, 0, 0);
    S[nt] = s;
  }

  // ---- mask (scale already folded into q): one query per lane ----
  const int qh = qh0 + (qi >> 3), qw = qw0 + (qi & 7);
  int sh = qh - 3; sh = sh < 0 ? 0 : (sh > 57 ? 57 : sh);
  int sw = qw - 3; sw = sw < 0 ? 0 : (sw > 57 ? 57 : sw);
  const int lo = sh - wh0;  // valid key-rows: nt in [lo, lo+7)
  bool wok[4];
#pragma unroll
  for (int reg = 0; reg < 4; ++reg) {
    int kw = wc0 + quad * 4 + reg;  // fixed key col per (lane,reg)
    wok[reg] = (kw >= sw) && (kw < sw + 7);
  }
  float mx[4] = {-1e30f, -1e30f, -1e30f, -1e30f};
#pragma unroll
  for (int nt = 0; nt < 14; ++nt) {
    bool rok = (unsigned)(nt - lo) < 7u;
#pragma unroll
    for (int reg = 0; reg < 4; ++reg) {
      float val = (rok && wok[reg]) ? S[nt][reg] : -1e30f;
      S[nt][reg] = val;
      mx[reg] = mx[reg] > val ? mx[reg] : val;
    }
  }
  float m = fmaxf(fmaxf(mx[0], mx[1]), fmaxf(mx[2], mx[3]));
  m = fmaxf(m, __shfl_xor(m, 16));
  m = fmaxf(m, __shfl_xor(m, 32));

  // ---- exp + row sum; pack UNNORMALIZED P (exp <= 1, bf16-safe) ----
  int plo[14], phi[14];
  float sm[4] = {0.f, 0.f, 0.f, 0.f};
#pragma unroll
  for (int nt = 0; nt < 14; ++nt) {
    float p0 = __expf(S[nt][0] - m);
    float p1 = __expf(S[nt][1] - m);
    float p2 = __expf(S[nt][2] - m);
    float p3 = __expf(S[nt][3] - m);
    sm[0] += p0; sm[1] += p1; sm[2] += p2; sm[3] += p3;
    bf16x2 a = {(__bf16)p0, (__bf16)p1};
    bf16x2 b = {(__bf16)p2, (__bf16)p3};
    plo[nt] = __builtin_bit_cast(int, a);
    phi[nt] = __builtin_bit_cast(int, b);
  }
  float ssum = (sm[0] + sm[1]) + (sm[2] + sm[3]);
  ssum += __shfl_xor(ssum, 16);
  ssum += __shfl_xor(ssum, 32);
  const float inv = 1.f / ssum;  // for q = wv*16 + n16

  __syncthreads();  // all waves done reading kwin
  // ---- V coop load: global -> vwin[dh][232] (key = kr*16+kc) ----
  const __bf16* vtb = vt + base;
#pragma unroll
  for (int i = 0; i < 7; ++i) {
    int c = i * 256 + tid;  // 1792 16-B chunks: c = dh*28 + kr*2 + half
    int dh = c / 28, rem = c % 28;
    int kr = rem >> 1, half = rem & 1;
    bf16x8 d = *(const bf16x8*)(vtb + (size_t)dh * 4096 +
                                (wh0 + kr) * 64 + wc0 + half * 8);
    *(bf16x8*)&r1[dh * 232 + kr * 16 + half * 8] = d;
  }
  __syncthreads();

  // ---- PV: O[16q x 64dh]; A-frag gathered in-register per kt ----
  // pa elem j = P[key=kt*32+quad*8+j][q=n16]. Source lane holds key-col
  // quad_s*4+reg at q=n16 -> gather from lanes s0=((quad&1)*2)*16+n16 and
  // s1=s0+16; key-row parity: quads 0,1 need nt=2kt, quads 2,3 nt=2kt+1.
  f32x4 O[4] = {{0.f, 0.f, 0.f, 0.f},
                {0.f, 0.f, 0.f, 0.f},
                {0.f, 0.f, 0.f, 0.f},
                {0.f, 0.f, 0.f, 0.f}};
  const int s0 = ((quad & 1) << 5) + n16;
  const int s1 = s0 + 16;
  const bool hiq = quad >= 2;
#pragma unroll
  for (int kt = 0; kt < 7; ++kt) {
    const int nA = 2 * kt, nB = 2 * kt + 1;
    int a0 = __shfl(plo[nA], s0), a1 = __shfl(phi[nA], s0);
    int a2 = __shfl(plo[nA], s1), a3 = __shfl(phi[nA], s1);
    int b0 = __shfl(plo[nB], s0), b1 = __shfl(phi[nB], s0);
    int b2 = __shfl(plo[nB], s1), b3 = __shfl(phi[nB], s1);
    i32x4 pu = {hiq ? b0 : a0, hiq ? b1 : a1, hiq ? b2 : a2, hiq ? b3 : a3};
    bf16x8 pa = __builtin_bit_cast(bf16x8, pu);
    const int key0 = kt * 32 + quad * 8;
#pragma unroll
    for (int ntv = 0; ntv < 4; ++ntv) {
      bf16x8 vb = *(const bf16x8*)&r1[(ntv * 16 + n16) * 232 + key0];
      O[ntv] = __builtin_amdgcn_mfma_f32_16x16x32_bf16(pa, vb, O[ntv], 0, 0, 0);
    }
  }

  // ---- deferred normalization: inv for O-row q'=quad*4+reg via shfl ----
  float invr[4];
#pragma unroll
  for (int reg = 0; reg < 4; ++reg) invr[reg] = __shfl(inv, quad * 4 + reg);

  // ---- epilogue: ao[b][s][head*64+dh] bf16 (O rows: q=quad*4+reg) ----
  const int b = bh >> 3, head = bh & 7;
#pragma unroll
  for (int ntv = 0; ntv < 4; ++ntv)
#pragma unroll
    for (int reg = 0; reg < 4; ++reg) {
      int qe = wv * 16 + quad * 4 + reg;
      int s_q = (qh0 + (qe >> 3)) * 64 + qw0 + (qe & 7);
      int dh = ntv * 16 + n16;
      out[((size_t)(b * 4096 + s_q)) * 512 + head * 64 + dh] =
          (__bf16)(O[ntv][reg] * invr[reg]);
    }
}

extern "C" void kernel_launch(void* const* d_in, const int* in_sizes, int n_in,
                              void* d_out, int out_size, void* d_ws,
                              size_t ws_size, hipStream_t stream) {
  const float* x = (const float*)d_in[0];      // [2,64,64,512] fp32
  const float* w_qkv = (const float*)d_in[1];  // [1536,512] fp32
  const float* w_out = (const float*)d_in[2];  // [512,512] fp32
  float* out = (float*)d_out;                  // [2,64,64,512] fp32

  const size_t qelems = (size_t)2 * 8 * 4096 * 64;  // 4,194,304
  __bf16* q = (__bf16*)d_ws;
  __bf16* k = q + qelems;
  __bf16* vt = k + qelems;          // V transposed [bh][dh][s]
  __bf16* xb = vt + qelems;         // converted x; reused as ao
  __bf16* wqb = xb + qelems;        // converted w_qkv
  __bf16* wob = wqb + 1536 * 512;   // converted w_out
  __bf16* ao = xb;                  // attn out aliases xb (x dead after QKV)

  // Stage 0: fused fp32 -> bf16 (655360 chunks of 2x f32x4)
  cvt_all<<<dim3(2560), dim3(256), 0, stream>>>(x, w_qkv, w_out, xb, wqb, wob);

  // Stage 1: QKV GEMM: 64 i-tiles x 12 e-tiles = 768 blocks (3/CU)
  gemm_lds<true, 128><<<dim3(768), dim3(256), 0, stream>>>(
      xb, wqb, q, k, vt, nullptr, 12);
  // Stage 2: MFMA attention: 16 bh * 64 tiles = 1024 workgroups (4/CU)
  attn_mfma<<<dim3(1024), dim3(256), 0, stream>>>(q, k, vt, ao);
  // Stage 3: out GEMM: 64 i-tiles x 8 e-tiles = 512 blocks
  gemm_lds<false, 64><<<dim3(512), dim3(256), 0, stream>>>(
      ao, wob, nullptr, nullptr, nullptr, out, 8);
}